// Round 10
// baseline (316.823 us; speedup 1.0000x reference)
//
#include <hip/hip_runtime.h>

// N=65536, D_IN=1024, D_LAT=128, K=512
#define NROWS 65536
#define DIN   1024
#define DLAT  128
#define KC    512

typedef __attribute__((ext_vector_type(8))) short bf16x8;
typedef __attribute__((ext_vector_type(4))) float f32x4;

__device__ inline short f2bf(float f) {
    unsigned u = __float_as_uint(f);
    return (short)((u + 0x7FFFu + ((u >> 16) & 1u)) >> 16);  // RNE f32->bf16
}

// pinned 16B global load: asm volatile cannot be sunk/elided by the scheduler.
// NOTE: no implicit wait — caller MUST s_waitcnt vmcnt(...) before using the result.
__device__ inline f32x4 gload16(const float* p) {
    f32x4 d;
    asm volatile("global_load_dwordx4 %0, %1, off" : "=v"(d) : "v"(p));
    return d;
}

#define MFMA __builtin_amdgcn_mfma_f32_16x16x32_bf16

// ---------- prep: Wt[n][k] = bf16(W[k][n]); cb = bf16(centroids) ----------
__global__ __launch_bounds__(256) void prep_convert(const float* __restrict__ W,
                                                    const float* __restrict__ C,
                                                    short* __restrict__ Wt,
                                                    short* __restrict__ cb) {
    int idx = blockIdx.x * 256 + threadIdx.x;
    if (idx < DLAT * DIN) {                 // Wt[n][k] = W[k][n]
        int n = idx >> 10, k = idx & 1023;
        Wt[idx] = f2bf(W[k * DLAT + n]);
    } else {
        int i2 = idx - DLAT * DIN;
        if (i2 < KC * DLAT) cb[i2] = f2bf(C[i2]);
    }
}

// ---------- prep: csq[k] = ||centroid_k||^2 ----------
__global__ __launch_bounds__(64) void prep_csq(const float* __restrict__ C,
                                               float* __restrict__ csq) {
    int row = blockIdx.x;
    int lane = threadIdx.x;
    float a = C[row * DLAT + lane];
    float b = C[row * DLAT + 64 + lane];
    float s = a * a + b * b;
    #pragma unroll
    for (int m = 32; m >= 1; m >>= 1) s += __shfl_xor(s, m, 64);
    if (lane == 0) csq[row] = s;
}

// ---------- K1: l = x @ W + b — barrier-free split-K, ASM-PINNED deep load queue ----------
// 512 thr / 8 waves, 16 rows/block (4096 blocks). Wave (ks4=w>>1, ch=w&1) owns
// K-slice [ks4*256,+256) x cols [ch*64,+64).
// x: 16 asm-volatile global_load_dwordx4 per thread (16 x 1KB contiguous per wave-instr),
// ALL issued before a single explicit vmcnt(0) -> ~128KB in flight per block. This is
// the Little's-law queue every prior round lost to compiler load-sinking (VGPR=52).
// W frags: plain C loads, each used once, L2-hot -> sinking them is fine.
// x tile: wave-private XOR-swizzled LDS (ch-twins write identical data, benign race).
// ONE __syncthreads total (split-K reduce).
__global__ __launch_bounds__(512, 2) void gemm1_pin(const float* __restrict__ x,
                                                    const short* __restrict__ Wt,
                                                    const float* __restrict__ bias,
                                                    float* __restrict__ lout) {
    __shared__ char lds[57344];   // 4 x 8KB swizzled x tiles + 24KB reduce buffer
    const int t = threadIdx.x;
    const int lane = t & 63, w = t >> 6;
    const int ks4 = w >> 1, ch = w & 1;
    const int l16 = lane & 15, lhi = lane >> 4;
    const int row0 = blockIdx.x * 16;
    const int kbase = ks4 * 256;

    // ---- pinned issue of all 16 x row-slice loads (deep queue) ----
    f32x4 xr[16];
    const float* xp = x + (long)row0 * DIN + kbase + (lane << 2);
    #pragma unroll
    for (int r = 0; r < 16; ++r) xr[r] = gload16(xp + (long)r * DIN);

    asm volatile("s_waitcnt vmcnt(0)" ::: "memory");
    __builtin_amdgcn_sched_barrier(0);   // rule #18: nothing below hoists above the wait

    // convert + swizzled ds_write into wave-private tile [16 rows][256 k] bf16
    // 16B granule g of row r stored at slot (g ^ r)
    short* xt = (short*)(lds + ks4 * 8192);
    #pragma unroll
    for (int r = 0; r < 16; ++r) {
        short4 o;
        o.x = f2bf(xr[r][0]); o.y = f2bf(xr[r][1]);
        o.z = f2bf(xr[r][2]); o.w = f2bf(xr[r][3]);
        *(short4*)((char*)xt + r * 512 + (((lane >> 1) ^ r) << 4) + ((lane & 1) << 3)) = o;
    }

    f32x4 acc[4];
    #pragma unroll
    for (int i = 0; i < 4; ++i) acc[i] = (f32x4){0.f, 0.f, 0.f, 0.f};

    // MFMA loop: A frags from own LDS tile (lgkm waits only), W frags plain loads (L2-hot)
    const short* wp = Wt + (long)(ch * 64 + l16) * DIN + kbase + lhi * 8;
    #pragma unroll
    for (int s = 0; s < 8; ++s) {
        const bf16x8 af = *(const bf16x8*)((char*)xt + l16 * 512
                                           + (((s * 4 + lhi) ^ l16) << 4));
        #pragma unroll
        for (int nb = 0; nb < 4; ++nb) {
            const bf16x8 bf = *(const bf16x8*)(wp + (long)(nb * 16) * DIN + s * 32);
            acc[nb] = MFMA(af, bf, acc[nb], 0, 0, 0);
        }
    }

    // split-K reduce across ks4 (one barrier), then bias + store by ks4==0 waves
    float* red = (float*)(lds + 32768);   // [3][2][4][64] x f32x4 = 24KB
    if (ks4 > 0) {
        #pragma unroll
        for (int nb = 0; nb < 4; ++nb)
            *(f32x4*)(red + ((((ks4 - 1) * 2 + ch) * 4 + nb) * 64 + lane) * 4) = acc[nb];
    }
    __syncthreads();
    if (ks4 == 0) {
        #pragma unroll
        for (int nb = 0; nb < 4; ++nb) {
            f32x4 a = acc[nb];
            #pragma unroll
            for (int p = 0; p < 3; ++p) {
                const f32x4 bvec = *(const f32x4*)(red + (((p * 2 + ch) * 4 + nb) * 64 + lane) * 4);
                a[0] += bvec[0]; a[1] += bvec[1]; a[2] += bvec[2]; a[3] += bvec[3];
            }
            const int col = ch * 64 + nb * 16 + l16;
            const float bv = bias[col];
            #pragma unroll
            for (int r = 0; r < 4; ++r)   // C/D: col=lane&15, row=(lane>>4)*4+reg
                lout[(long)(row0 + lhi * 4 + r) * DLAT + col] = a[r] + bv;
        }
    }
}

// ---------- K2: S = l @ c^T; D; num=1/(1+D); Q=num/rowsum; Fq partials ----------
__global__ __launch_bounds__(256, 1) void gemm2_q(const float* __restrict__ lout,
                                                  const short* __restrict__ cb,
                                                  const float* __restrict__ csq,
                                                  float* __restrict__ Qout,
                                                  float* __restrict__ partial) {
    const int wid = threadIdx.x >> 6, lane = threadIdx.x & 63;
    const int l16 = lane & 15, lhi = lane >> 4;
    const int row0 = blockIdx.x * 64 + wid * 16;

    bf16x8 af[4];
    float sq = 0.f;
    const float* lrow = lout + (long)(row0 + l16) * DLAT;
    #pragma unroll
    for (int ks = 0; ks < 4; ++ks) {
        const float4* lp = (const float4*)(lrow + ks * 32 + lhi * 8);
        float4 v0 = lp[0], v1 = lp[1];
        sq += v0.x * v0.x + v0.y * v0.y + v0.z * v0.z + v0.w * v0.w
            + v1.x * v1.x + v1.y * v1.y + v1.z * v1.z + v1.w * v1.w;
        bf16x8 a;
        a[0] = f2bf(v0.x); a[1] = f2bf(v0.y); a[2] = f2bf(v0.z); a[3] = f2bf(v0.w);
        a[4] = f2bf(v1.x); a[5] = f2bf(v1.y); a[6] = f2bf(v1.z); a[7] = f2bf(v1.w);
        af[ks] = a;
    }
    sq += __shfl_xor(sq, 16, 64);
    sq += __shfl_xor(sq, 32, 64);          // lane L holds lsq of row (L&15)
    float lsqr[4];
    #pragma unroll
    for (int r = 0; r < 4; ++r) lsqr[r] = __shfl(sq, lhi * 4 + r, 64);

    f32x4 numv[32];
    float rsum[4] = {0.f, 0.f, 0.f, 0.f};
    #pragma unroll
    for (int nb = 0; nb < 32; ++nb) {
        f32x4 acc = (f32x4){0.f, 0.f, 0.f, 0.f};
        const short* cbase = cb + (nb * 16 + l16) * DLAT;
        #pragma unroll
        for (int ks = 0; ks < 4; ++ks) {
            const bf16x8 bf = *(const bf16x8*)(cbase + ks * 32 + lhi * 8);
            acc = MFMA(af[ks], bf, acc, 0, 0, 0);
        }
        float cs = csq[nb * 16 + l16];
        f32x4 nm;
        #pragma unroll
        for (int r = 0; r < 4; ++r) {
            float Dv = lsqr[r] + cs - 2.f * acc[r];
            float v = 1.f / (1.f + Dv);    // alpha=1: (1+D)^(-1)
            nm[r] = v;
            rsum[r] += v;
        }
        numv[nb] = nm;
    }
    #pragma unroll
    for (int m = 1; m <= 8; m <<= 1) {
        #pragma unroll
        for (int r = 0; r < 4; ++r) rsum[r] += __shfl_xor(rsum[r], m, 64);
    }
    float inv[4];
    #pragma unroll
    for (int r = 0; r < 4; ++r) inv[r] = 1.f / rsum[r];

    __shared__ float lds_fq[4][KC];
    #pragma unroll
    for (int nb = 0; nb < 32; ++nb) {
        float cp = 0.f;
        #pragma unroll
        for (int r = 0; r < 4; ++r) {
            float q = numv[nb][r] * inv[r];
            Qout[(long)(row0 + lhi * 4 + r) * KC + nb * 16 + l16] = q;
            cp += q;
        }
        cp += __shfl_xor(cp, 16, 64);
        cp += __shfl_xor(cp, 32, 64);      // colsum over this wave's 16 rows
        if (lhi == 0) lds_fq[wid][nb * 16 + l16] = cp;
    }
    __syncthreads();
    for (int c = threadIdx.x; c < KC; c += 256) {
        partial[(long)blockIdx.x * KC + c] =
            lds_fq[0][c] + lds_fq[1][c] + lds_fq[2][c] + lds_fq[3][c];
    }
}

// ---------- K3: Fq[c] = sum over 1024 block partials (deterministic tree) ----------
__global__ __launch_bounds__(256) void fq_reduce(const float* __restrict__ partial,
                                                 float* __restrict__ fq) {
    int c = blockIdx.x;
    float s = 0.f;
    #pragma unroll
    for (int i = 0; i < 4; ++i) s += partial[(long)(threadIdx.x + i * 256) * KC + c];
    __shared__ float red[256];
    red[threadIdx.x] = s;
    __syncthreads();
    for (int off = 128; off >= 1; off >>= 1) {
        if (threadIdx.x < off) red[threadIdx.x] += red[threadIdx.x + off];
        __syncthreads();
    }
    if (threadIdx.x == 0) fq[c] = red[0];
}

// ---------- K4: P = rownorm(Q^2 / Fq) ----------
__global__ __launch_bounds__(256) void p_kernel(const float* __restrict__ Q,
                                                const float* __restrict__ fq,
                                                float* __restrict__ P) {
    const int wid = threadIdx.x >> 6, lane = threadIdx.x & 63;
    const int gw = blockIdx.x * 4 + wid;   // 8192 waves, each does 8 rows
    const float4 f0 = *(const float4*)(fq + lane * 8);
    const float4 f1 = *(const float4*)(fq + lane * 8 + 4);
    float inv[8] = {1.f / f0.x, 1.f / f0.y, 1.f / f0.z, 1.f / f0.w,
                    1.f / f1.x, 1.f / f1.y, 1.f / f1.z, 1.f / f1.w};
    for (int it = 0; it < 8; ++it) {
        const long row = gw + (long)it * 8192;
        const float4* qp = (const float4*)(Q + row * KC + lane * 8);
        float4 q0 = qp[0], q1 = qp[1];
        float n[8];
        n[0] = q0.x * q0.x * inv[0]; n[1] = q0.y * q0.y * inv[1];
        n[2] = q0.z * q0.z * inv[2]; n[3] = q0.w * q0.w * inv[3];
        n[4] = q1.x * q1.x * inv[4]; n[5] = q1.y * q1.y * inv[5];
        n[6] = q1.z * q1.z * inv[6]; n[7] = q1.w * q1.w * inv[7];
        float rs = n[0] + n[1] + n[2] + n[3] + n[4] + n[5] + n[6] + n[7];
        #pragma unroll
        for (int m = 1; m <= 32; m <<= 1) rs += __shfl_xor(rs, m, 64);
        float ir = 1.f / rs;
        float4 o0 = {n[0] * ir, n[1] * ir, n[2] * ir, n[3] * ir};
        float4 o1 = {n[4] * ir, n[5] * ir, n[6] * ir, n[7] * ir};
        float4* pp = (float4*)(P + row * KC + lane * 8);
        pp[0] = o0; pp[1] = o1;
    }
}

extern "C" void kernel_launch(void* const* d_in, const int* in_sizes, int n_in,
                              void* d_out, int out_size, void* d_ws, size_t ws_size,
                              hipStream_t stream) {
    const float* x  = (const float*)d_in[0];
    const float* W  = (const float*)d_in[1];
    const float* b  = (const float*)d_in[2];
    const float* C  = (const float*)d_in[3];

    float* out  = (float*)d_out;
    float* lout = out;                                   // 65536*128
    float* Qout = out + (long)NROWS * DLAT;              // 65536*512
    float* Pout = Qout + (long)NROWS * KC;               // 65536*512

    // workspace layout (~2.44 MB)
    char*  ws      = (char*)d_ws;
    short* Wt      = (short*)ws;                         // 131072 * 2 B
    short* cb      = (short*)(ws + 262144);              // 65536 * 2 B
    float* csq     = (float*)(ws + 262144 + 131072);     // 512 * 4 B
    float* partial = (float*)(ws + 395264);              // 1024*512*4 = 2 MB
    float* fq      = (float*)(ws + 395264 + 2097152);    // 512 * 4 B

    hipLaunchKernelGGL(prep_convert, dim3(768),  dim3(256), 0, stream, W, C, Wt, cb);
    hipLaunchKernelGGL(prep_csq,     dim3(512),  dim3(64),  0, stream, C, csq);
    hipLaunchKernelGGL(gemm1_pin,    dim3(4096), dim3(512), 0, stream, x, Wt, b, lout);
    hipLaunchKernelGGL(gemm2_q,      dim3(1024), dim3(256), 0, stream, lout, cb, csq, Qout, partial);
    hipLaunchKernelGGL(fq_reduce,    dim3(512),  dim3(256), 0, stream, partial, fq);
    hipLaunchKernelGGL(p_kernel,     dim3(2048), dim3(256), 0, stream, Qout, fq, Pout);
}

// Round 11
// 306.844 us; speedup vs baseline: 1.0325x; 1.0325x over previous
//
#include <hip/hip_runtime.h>

// N=65536, D_IN=1024, D_LAT=128, K=512
#define NROWS 65536
#define DIN   1024
#define DLAT  128
#define KC    512

typedef __attribute__((ext_vector_type(8))) short bf16x8;
typedef __attribute__((ext_vector_type(4))) float f32x4;

// direct global->LDS DMA, 16B per lane, LDS dest = wave-uniform base + lane*16
#define GLDS16(gp, lp)                                                          \
    __builtin_amdgcn_global_load_lds((const __attribute__((address_space(1))) void*)(gp), \
                                     (__attribute__((address_space(3))) void*)(lp), 16, 0, 0)

__device__ inline short f2bf(float f) {
    unsigned u = __float_as_uint(f);
    return (short)((u + 0x7FFFu + ((u >> 16) & 1u)) >> 16);  // RNE f32->bf16
}

#define MFMA __builtin_amdgcn_mfma_f32_16x16x32_bf16

// ---------- prep: Wt[n][k] = bf16(W[k][n]); cb = bf16(centroids) ----------
__global__ __launch_bounds__(256) void prep_convert(const float* __restrict__ W,
                                                    const float* __restrict__ C,
                                                    short* __restrict__ Wt,
                                                    short* __restrict__ cb) {
    int idx = blockIdx.x * 256 + threadIdx.x;
    if (idx < DLAT * DIN) {                 // Wt[n][k] = W[k][n]
        int n = idx >> 10, k = idx & 1023;
        Wt[idx] = f2bf(W[k * DLAT + n]);
    } else {
        int i2 = idx - DLAT * DIN;
        if (i2 < KC * DLAT) cb[i2] = f2bf(C[i2]);
    }
}

// ---------- prep: csq[k] = ||centroid_k||^2 ----------
__global__ __launch_bounds__(64) void prep_csq(const float* __restrict__ C,
                                               float* __restrict__ csq) {
    int row = blockIdx.x;
    int lane = threadIdx.x;
    float a = C[row * DLAT + lane];
    float b = C[row * DLAT + 64 + lane];
    float s = a * a + b * b;
    #pragma unroll
    for (int m = 32; m >= 1; m >>= 1) s += __shfl_xor(s, m, 64);
    if (lane == 0) csq[row] = s;
}

// ---------- K1: l = x @ W + b — WHOLE-ROW x staging (burst-length experiment) ----------
// 16 rows/block (4096 blocks), 256 thr / 4 waves. The block's x-tile (16 x 4KB = 64KB
// f32) is staged ONCE up-front: per j, the 256 threads stage one ENTIRE contiguous
// 4KB row via global_load_lds (unsinkable — no dest VGPR), granule-XOR applied on the
// global source (rule #21; read side uses the same involution). Every prior round
// consumed x as 256-512B strips at 4KB stride (page-activate-bound, ~2.3 TB/s);
// this makes each row one full-size burst. W: BK=32 chunks (8KB, L2-hot) double-
// buffered with r3's proven 2-barrier cadence. LDS 80KB -> 2 blocks/CU.
__global__ __launch_bounds__(256) void gemm1_row(const float* __restrict__ x,
                                                 const short* __restrict__ Wt,
                                                 const float* __restrict__ bias,
                                                 float* __restrict__ lout) {
    __shared__ char lds[81920];          // [0,64K) x tile; [64K,80K) W dbuf 2x8KB
    char* wlds = lds + 65536;
    const int t = threadIdx.x;
    const int lane = t & 63, wid = t >> 6;
    const int l16 = lane & 15, lhi = lane >> 4;
    const int row0 = blockIdx.x * 16;

    // ---- stage x: 16 whole rows, one per j; thread t handles 16B granule t of row j.
    // source granule = t ^ (j&15) (XOR within 256B window); LDS linear dest.
    #pragma unroll
    for (int j = 0; j < 16; ++j) {
        GLDS16(x + (long)(row0 + j) * DIN + ((t ^ j) << 2),
               lds + (j * 256 + t) * 16);
    }

    // ---- stage W chunk 0 (8KB = 512 granules; 2 per thread) ----
    #define WSTAGE(kc) { _Pragma("unroll")                                      \
        for (int j2 = 0; j2 < 2; ++j2) {                                        \
            const int G2 = j2 * 256 + t;                                        \
            const int n = G2 >> 2, s2 = G2 & 3;                                 \
            GLDS16(Wt + (long)n * DIN + (kc) * 32 + ((s2 ^ (n & 3)) << 3),      \
                   wlds + ((kc) & 1) * 8192 + G2 * 16);                         \
        } }
    WSTAGE(0);
    __syncthreads();   // drains x tile + W chunk 0 (vmcnt(0) at barrier)

    f32x4 acc[2];
    acc[0] = (f32x4){0.f, 0.f, 0.f, 0.f};
    acc[1] = (f32x4){0.f, 0.f, 0.f, 0.f};

    const float* xf = (const float*)lds;
    for (int kc = 0; kc < 32; ++kc) {
        if (kc < 31) WSTAGE(kc + 1);   // L2-hot, lands by the end-of-iter barrier

        // A frag: row l16, global granules h, h+1 (h = kc*8 + lhi*2) -> slot h^row
        const int h = kc * 8 + lhi * 2;
        const float4 va0 = *(const float4*)(xf + (l16 * 256 + ((h    ) ^ l16)) * 4);
        const float4 va1 = *(const float4*)(xf + (l16 * 256 + ((h + 1) ^ l16)) * 4);
        bf16x8 af;
        af[0] = f2bf(va0.x); af[1] = f2bf(va0.y); af[2] = f2bf(va0.z); af[3] = f2bf(va0.w);
        af[4] = f2bf(va1.x); af[5] = f2bf(va1.y); af[6] = f2bf(va1.z); af[7] = f2bf(va1.w);

        const char* wb = wlds + (kc & 1) * 8192;
        #pragma unroll
        for (int ct = 0; ct < 2; ++ct) {
            const int n = wid * 32 + ct * 16 + l16;
            const bf16x8 bf = *(const bf16x8*)(wb + n * 64 + ((lhi ^ (n & 3)) << 4));
            acc[ct] = MFMA(af, bf, acc[ct], 0, 0, 0);
        }
        __syncthreads();   // all waves done with wbuf[kc&1]; W(kc+1) landed
    }
    #undef WSTAGE

    #pragma unroll
    for (int ct = 0; ct < 2; ++ct) {
        const int col = wid * 32 + ct * 16 + l16;
        const float bv = bias[col];
        #pragma unroll
        for (int r = 0; r < 4; ++r)   // C/D: col=lane&15, row=(lane>>4)*4+reg
            lout[(long)(row0 + lhi * 4 + r) * DLAT + col] = acc[ct][r] + bv;
    }
}

// ---------- K2: S = l @ c^T; D; num=1/(1+D); Q=num/rowsum; Fq partials ----------
__global__ __launch_bounds__(256, 1) void gemm2_q(const float* __restrict__ lout,
                                                  const short* __restrict__ cb,
                                                  const float* __restrict__ csq,
                                                  float* __restrict__ Qout,
                                                  float* __restrict__ partial) {
    const int wid = threadIdx.x >> 6, lane = threadIdx.x & 63;
    const int l16 = lane & 15, lhi = lane >> 4;
    const int row0 = blockIdx.x * 64 + wid * 16;

    bf16x8 af[4];
    float sq = 0.f;
    const float* lrow = lout + (long)(row0 + l16) * DLAT;
    #pragma unroll
    for (int ks = 0; ks < 4; ++ks) {
        const float4* lp = (const float4*)(lrow + ks * 32 + lhi * 8);
        float4 v0 = lp[0], v1 = lp[1];
        sq += v0.x * v0.x + v0.y * v0.y + v0.z * v0.z + v0.w * v0.w
            + v1.x * v1.x + v1.y * v1.y + v1.z * v1.z + v1.w * v1.w;
        bf16x8 a;
        a[0] = f2bf(v0.x); a[1] = f2bf(v0.y); a[2] = f2bf(v0.z); a[3] = f2bf(v0.w);
        a[4] = f2bf(v1.x); a[5] = f2bf(v1.y); a[6] = f2bf(v1.z); a[7] = f2bf(v1.w);
        af[ks] = a;
    }
    sq += __shfl_xor(sq, 16, 64);
    sq += __shfl_xor(sq, 32, 64);          // lane L holds lsq of row (L&15)
    float lsqr[4];
    #pragma unroll
    for (int r = 0; r < 4; ++r) lsqr[r] = __shfl(sq, lhi * 4 + r, 64);

    f32x4 numv[32];
    float rsum[4] = {0.f, 0.f, 0.f, 0.f};
    #pragma unroll
    for (int nb = 0; nb < 32; ++nb) {
        f32x4 acc = (f32x4){0.f, 0.f, 0.f, 0.f};
        const short* cbase = cb + (nb * 16 + l16) * DLAT;
        #pragma unroll
        for (int ks = 0; ks < 4; ++ks) {
            const bf16x8 bf = *(const bf16x8*)(cbase + ks * 32 + lhi * 8);
            acc = MFMA(af[ks], bf, acc, 0, 0, 0);
        }
        float cs = csq[nb * 16 + l16];
        f32x4 nm;
        #pragma unroll
        for (int r = 0; r < 4; ++r) {
            float Dv = lsqr[r] + cs - 2.f * acc[r];
            float v = 1.f / (1.f + Dv);    // alpha=1: (1+D)^(-1)
            nm[r] = v;
            rsum[r] += v;
        }
        numv[nb] = nm;
    }
    #pragma unroll
    for (int m = 1; m <= 8; m <<= 1) {
        #pragma unroll
        for (int r = 0; r < 4; ++r) rsum[r] += __shfl_xor(rsum[r], m, 64);
    }
    float inv[4];
    #pragma unroll
    for (int r = 0; r < 4; ++r) inv[r] = 1.f / rsum[r];

    __shared__ float lds_fq[4][KC];
    #pragma unroll
    for (int nb = 0; nb < 32; ++nb) {
        float cp = 0.f;
        #pragma unroll
        for (int r = 0; r < 4; ++r) {
            float q = numv[nb][r] * inv[r];
            Qout[(long)(row0 + lhi * 4 + r) * KC + nb * 16 + l16] = q;
            cp += q;
        }
        cp += __shfl_xor(cp, 16, 64);
        cp += __shfl_xor(cp, 32, 64);      // colsum over this wave's 16 rows
        if (lhi == 0) lds_fq[wid][nb * 16 + l16] = cp;
    }
    __syncthreads();
    for (int c = threadIdx.x; c < KC; c += 256) {
        partial[(long)blockIdx.x * KC + c] =
            lds_fq[0][c] + lds_fq[1][c] + lds_fq[2][c] + lds_fq[3][c];
    }
}

// ---------- K3: Fq[c] = sum over 1024 block partials (deterministic tree) ----------
__global__ __launch_bounds__(256) void fq_reduce(const float* __restrict__ partial,
                                                 float* __restrict__ fq) {
    int c = blockIdx.x;
    float s = 0.f;
    #pragma unroll
    for (int i = 0; i < 4; ++i) s += partial[(long)(threadIdx.x + i * 256) * KC + c];
    __shared__ float red[256];
    red[threadIdx.x] = s;
    __syncthreads();
    for (int off = 128; off >= 1; off >>= 1) {
        if (threadIdx.x < off) red[threadIdx.x] += red[threadIdx.x + off];
        __syncthreads();
    }
    if (threadIdx.x == 0) fq[c] = red[0];
}

// ---------- K4: P = rownorm(Q^2 / Fq) ----------
__global__ __launch_bounds__(256) void p_kernel(const float* __restrict__ Q,
                                                const float* __restrict__ fq,
                                                float* __restrict__ P) {
    const int wid = threadIdx.x >> 6, lane = threadIdx.x & 63;
    const int gw = blockIdx.x * 4 + wid;   // 8192 waves, each does 8 rows
    const float4 f0 = *(const float4*)(fq + lane * 8);
    const float4 f1 = *(const float4*)(fq + lane * 8 + 4);
    float inv[8] = {1.f / f0.x, 1.f / f0.y, 1.f / f0.z, 1.f / f0.w,
                    1.f / f1.x, 1.f / f1.y, 1.f / f1.z, 1.f / f1.w};
    for (int it = 0; it < 8; ++it) {
        const long row = gw + (long)it * 8192;
        const float4* qp = (const float4*)(Q + row * KC + lane * 8);
        float4 q0 = qp[0], q1 = qp[1];
        float n[8];
        n[0] = q0.x * q0.x * inv[0]; n[1] = q0.y * q0.y * inv[1];
        n[2] = q0.z * q0.z * inv[2]; n[3] = q0.w * q0.w * inv[3];
        n[4] = q1.x * q1.x * inv[4]; n[5] = q1.y * q1.y * inv[5];
        n[6] = q1.z * q1.z * inv[6]; n[7] = q1.w * q1.w * inv[7];
        float rs = n[0] + n[1] + n[2] + n[3] + n[4] + n[5] + n[6] + n[7];
        #pragma unroll
        for (int m = 1; m <= 32; m <<= 1) rs += __shfl_xor(rs, m, 64);
        float ir = 1.f / rs;
        float4 o0 = {n[0] * ir, n[1] * ir, n[2] * ir, n[3] * ir};
        float4 o1 = {n[4] * ir, n[5] * ir, n[6] * ir, n[7] * ir};
        float4* pp = (float4*)(P + row * KC + lane * 8);
        pp[0] = o0; pp[1] = o1;
    }
}

extern "C" void kernel_launch(void* const* d_in, const int* in_sizes, int n_in,
                              void* d_out, int out_size, void* d_ws, size_t ws_size,
                              hipStream_t stream) {
    const float* x  = (const float*)d_in[0];
    const float* W  = (const float*)d_in[1];
    const float* b  = (const float*)d_in[2];
    const float* C  = (const float*)d_in[3];

    float* out  = (float*)d_out;
    float* lout = out;                                   // 65536*128
    float* Qout = out + (long)NROWS * DLAT;              // 65536*512
    float* Pout = Qout + (long)NROWS * KC;               // 65536*512

    // workspace layout (~2.44 MB)
    char*  ws      = (char*)d_ws;
    short* Wt      = (short*)ws;                         // 131072 * 2 B
    short* cb      = (short*)(ws + 262144);              // 65536 * 2 B
    float* csq     = (float*)(ws + 262144 + 131072);     // 512 * 4 B
    float* partial = (float*)(ws + 395264);              // 1024*512*4 = 2 MB
    float* fq      = (float*)(ws + 395264 + 2097152);    // 512 * 4 B

    hipLaunchKernelGGL(prep_convert, dim3(768),  dim3(256), 0, stream, W, C, Wt, cb);
    hipLaunchKernelGGL(prep_csq,     dim3(512),  dim3(64),  0, stream, C, csq);
    hipLaunchKernelGGL(gemm1_row,    dim3(4096), dim3(256), 0, stream, x, Wt, b, lout);
    hipLaunchKernelGGL(gemm2_q,      dim3(1024), dim3(256), 0, stream, lout, cb, csq, Qout, partial);
    hipLaunchKernelGGL(fq_reduce,    dim3(512),  dim3(256), 0, stream, partial, fq);
    hipLaunchKernelGGL(p_kernel,     dim3(2048), dim3(256), 0, stream, Qout, fq, Pout);
}